// Round 16
// baseline (549.504 us; speedup 1.0000x reference)
//
#include <hip/hip_runtime.h>

typedef __attribute__((ext_vector_type(4))) float f32x4;
typedef __attribute__((ext_vector_type(8))) _Float16 f16x8;

#define D 256          // D_in == D_out == 256
#define VBS 128        // ghost batch rows per chunk
#define BN_EPS 1e-5f

// ---------------------------------------------------------------- pack W
// Pack W[k][n] (f32, row-major 256x256) into f16 MFMA fragment order.
// frag value = W[kb*32+(l>>4)*8+j][ct*16+(l&15)], frag (kb,ct,lane) at
// wp + ((kb*16+ct)*64+lane)*8.
__global__ void pack_w_kernel(const float* __restrict__ W, _Float16* __restrict__ wp) {
    int idx = blockIdx.x * blockDim.x + threadIdx.x;   // [0, 8192)
    int kb  = idx >> 10;
    int rem = idx & 1023;
    int ct  = rem >> 6;
    int l   = rem & 63;
    int col = ct * 16 + (l & 15);
    int k0  = kb * 32 + ((l >> 4) << 3);
    f16x8 v;
#pragma unroll
    for (int j = 0; j < 8; ++j) v[j] = (_Float16)W[(k0 + j) * D + col];
    *reinterpret_cast<f16x8*>(wp + (size_t)idx * 8) = v;
}

// 16-lane (DPP row) all-lanes sum: VALU pipe only.
template <int CTRL>
__device__ __forceinline__ float row_ror_add(float x) {
    int v = __builtin_amdgcn_update_dpp(0, __builtin_bit_cast(int, x),
                                        CTRL, 0xF, 0xF, true);
    return x + __builtin_bit_cast(float, v);
}
__device__ __forceinline__ float rsum16(float x) {
    x = row_ror_add<0x128>(x);
    x = row_ror_add<0x124>(x);
    x = row_ror_add<0x122>(x);
    x = row_ror_add<0x121>(x);
    return x;
}

#define GLL16(g, l)                                                     \
    __builtin_amdgcn_global_load_lds(                                   \
        (const __attribute__((address_space(1))) unsigned*)(g),         \
        (__attribute__((address_space(3))) unsigned*)(l), 16, 0, 0)

#define RAWBAR() do {                                          \
        asm volatile("s_waitcnt lgkmcnt(0)" ::: "memory");     \
        __builtin_amdgcn_s_barrier();                          \
        asm volatile("" ::: "memory");                         \
    } while (0)

// LDS map (bytes):
//   [0,131072)        full packed W, resident for the whole kernel
//   [131072,147456)   sSum[16][256]  (shared by stats round 1 AND round 2)
//   [147456,149504)   sMean[2][256]
//   [149504,151552)   sA[2][256]     [151552,153600) sB[2][256]
//
// 1024 threads = 16 waves = 2 chunk-groups x 8 waves (4 waves/SIMD, 1 blk/CU).
// W staged into LDS ONCE; per iteration the block does TWO chunks:
//   - barrier-free fully-unrolled K-loop (W read-only, a in 2-deep reg window)
//   - stats in two rounds (sum, then sumsq) through one [16][256] buffer
//     with raw lgkmcnt-only barriers (in-flight vmem never drained)
//   - priors JIT in batches of 4 (bounded regs, 4 loads in flight)
// TRANSPOSED mfma: acc[ct] = mfma(W-frag, a-frag); lane = row, cols
// ct*16 + (lane>>4)*4 + {0..3}.  Register budget 128/thread at 4 w/SIMD.
__global__ __launch_bounds__(1024)
void fused_kernel(const float* __restrict__ A, const float* __restrict__ priors,
                  const _Float16* __restrict__ Wp, const float* __restrict__ gamma,
                  const float* __restrict__ beta, float* __restrict__ out, int iters) {
    const int tid  = threadIdx.x;
    const int lane = tid & 63;
    const int wid  = tid >> 6;     // 0..15
    const int sub  = wid >> 3;     // chunk-group 0/1
    const int wv   = wid & 7;      // wave within group
    const int lrow = lane & 15;
    const int q    = lane >> 4;

    __shared__ char smem[153600];

    // ---- prologue: stage the full 128 KB W into LDS once ----
    {
        const char* ws = (const char*)Wp + (size_t)tid * 16;
        char* wd = smem + (size_t)tid * 16;
#pragma unroll
        for (int j = 0; j < 8; ++j) GLL16(ws + j * 16384, wd + j * 16384);
    }
    __syncthreads();   // one-time drain; W is read-only from here on

    float* sSum  = (float*)(smem + 131072);   // [16][256], two rounds
    float* sMean = (float*)(smem + 147456);   // [2][256]
    float* sA    = (float*)(smem + 149504);   // [2][256]
    float* sB    = (float*)(smem + 151552);   // [2][256]

    const int c0 = blockIdx.x;
    const int GRID = gridDim.x;
    // this thread's a-row: chunkpair*256 + sub*128 + wv*16 + lrow
    const float* abase = A + (size_t)(c0 * 2 * VBS + sub * VBS + wv * 16 + lrow) * D + q * 8;
    const size_t CSTR = (size_t)GRID * 2 * VBS * D;   // floats per iteration

    // 2-deep rotating a window (named slots -> static indexing)
    f32x4 aL0, aH0, aL1, aH1;
    aL0 = *reinterpret_cast<const f32x4*>(abase);
    aH0 = *reinterpret_cast<const f32x4*>(abase + 4);
    aL1 = *reinterpret_cast<const f32x4*>(abase + 32);
    aH1 = *reinterpret_cast<const f32x4*>(abase + 36);

#pragma unroll 1
    for (int it = 0; it < iters; ++it) {
        const int myrow = (c0 + it * GRID) * 2 * VBS + sub * VBS + wv * 16 + lrow;
        const float* ac = abase + (size_t)it * CSTR;

        f32x4 acc[16];
#pragma unroll
        for (int ct = 0; ct < 16; ++ct) { f32x4 z = {0.f, 0.f, 0.f, 0.f}; acc[ct] = z; }

        // ---- K-loop: barrier-free; a window rotates 2 steps ahead ----
#pragma unroll
        for (int kb = 0; kb < 8; ++kb) {
            f32x4 al = (kb & 1) ? aL1 : aL0;
            f32x4 ah = (kb & 1) ? aH1 : aH0;
            f16x8 t;
#pragma unroll
            for (int j = 0; j < 4; ++j) { t[j] = (_Float16)al[j]; t[j + 4] = (_Float16)ah[j]; }
            if (kb < 6) {   // refill the slot just consumed with step kb+2
                const float* an = ac + (kb + 2) * 32;
                if (kb & 1) { aL1 = *reinterpret_cast<const f32x4*>(an);
                              aH1 = *reinterpret_cast<const f32x4*>(an + 4); }
                else        { aL0 = *reinterpret_cast<const f32x4*>(an);
                              aH0 = *reinterpret_cast<const f32x4*>(an + 4); }
            }
            const char* wb = smem + kb * 16384 + lane * 16;
#pragma unroll
            for (int ct = 0; ct < 16; ++ct) {
                f16x8 w = *reinterpret_cast<const f16x8*>(wb + ct * 1024);
                acc[ct] = __builtin_amdgcn_mfma_f32_16x16x32_f16(w, t, acc[ct], 0, 0, 0);
            }
        }

        // ---- next iteration's first a window: flies through the barriers ----
        if (it + 1 < iters) {
            const float* an = ac + CSTR;
            aL0 = *reinterpret_cast<const f32x4*>(an);
            aH0 = *reinterpret_cast<const f32x4*>(an + 4);
            aL1 = *reinterpret_cast<const f32x4*>(an + 32);
            aH1 = *reinterpret_cast<const f32x4*>(an + 36);
        }

        // ---- stats round 1: column sums ----
#pragma unroll
        for (int ct = 0; ct < 16; ++ct) {
            f32x4 s = acc[ct];
#pragma unroll
            for (int c = 0; c < 4; ++c) s[c] = rsum16(s[c]);
            if (lrow == 0)
                *reinterpret_cast<f32x4*>(&sSum[wid * D + ct * 16 + q * 4]) = s;
        }
        RAWBAR();
        if (tid < 512) {
            const int s2 = tid >> 8, cc = tid & 255;
            float s = 0.f;
#pragma unroll
            for (int w = 0; w < 8; ++w) s += sSum[(s2 * 8 + w) * D + cc];
            sMean[s2 * D + cc] = s * (1.0f / 128.0f);
        }
        RAWBAR();   // sSum reads done; safe to overwrite in round 2

        // ---- stats round 2: column sum-of-squares ----
#pragma unroll
        for (int ct = 0; ct < 16; ++ct) {
            f32x4 qv = acc[ct] * acc[ct];
#pragma unroll
            for (int c = 0; c < 4; ++c) qv[c] = rsum16(qv[c]);
            if (lrow == 0)
                *reinterpret_cast<f32x4*>(&sSum[wid * D + ct * 16 + q * 4]) = qv;
        }
        RAWBAR();
        if (tid < 512) {
            const int s2 = tid >> 8, cc = tid & 255;
            float qq = 0.f;
#pragma unroll
            for (int w = 0; w < 8; ++w) qq += sSum[(s2 * 8 + w) * D + cc];
            float mean = sMean[s2 * D + cc];
            float var  = qq * (1.0f / 128.0f) - mean * mean;
            float g    = gamma[cc] * rsqrtf(var + BN_EPS);
            sA[s2 * D + cc] = g;
            sB[s2 * D + cc] = beta[cc] - mean * g;
        }
        RAWBAR();

        // ---- apply BN * priors (JIT, batches of 4); track row max + sum ----
        const float* prb = priors + (size_t)myrow * D;
        const float* sAc = sA + sub * D;
        const float* sBc = sB + sub * D;
        float m = -1e30f, ssum = 0.f;
#pragma unroll 1
        for (int g4 = 0; g4 < 4; ++g4) {
            f32x4 pv0 = *reinterpret_cast<const f32x4*>(prb + (g4 * 4 + 0) * 16 + q * 4);
            f32x4 pv1 = *reinterpret_cast<const f32x4*>(prb + (g4 * 4 + 1) * 16 + q * 4);
            f32x4 pv2 = *reinterpret_cast<const f32x4*>(prb + (g4 * 4 + 2) * 16 + q * 4);
            f32x4 pv3 = *reinterpret_cast<const f32x4*>(prb + (g4 * 4 + 3) * 16 + q * 4);
#pragma unroll
            for (int j = 0; j < 4; ++j) {
                const int ct = g4 * 4 + j;
                const int cc = ct * 16 + q * 4;
                f32x4 ga = *reinterpret_cast<const f32x4*>(&sAc[cc]);
                f32x4 bb = *reinterpret_cast<const f32x4*>(&sBc[cc]);
                f32x4 pv = (j == 0) ? pv0 : (j == 1) ? pv1 : (j == 2) ? pv2 : pv3;
                f32x4 x  = (acc[ct] * ga + bb) * pv;
                acc[ct] = x;
                m = fmaxf(m, fmaxf(fmaxf(x[0], x[1]), fmaxf(x[2], x[3])));
                ssum += (x[0] + x[1]) + (x[2] + x[3]);
            }
        }
        m = fmaxf(m, __shfl_xor(m, 16));
        m = fmaxf(m, __shfl_xor(m, 32));
        ssum += __shfl_xor(ssum, 16);
        ssum += __shfl_xor(ssum, 32);

        // Michelot fixed-point. Both seeds provably <= tau*:
        //   m-1 (max support) and (sum_all-1)/256 (full support step).
        float tau = fmaxf(m - 1.0f, (ssum - 1.0f) * (1.0f / 256.0f));
#pragma unroll 1
        for (int itr = 0; itr < 32; ++itr) {
            float s = 0.f, c = 0.f;
#pragma unroll
            for (int ct = 0; ct < 16; ++ct)
#pragma unroll
                for (int k = 0; k < 4; ++k) {
                    float zz = acc[ct][k];
                    if (zz > tau) { s += zz; c += 1.f; }
                }
            s += __shfl_xor(s, 16); c += __shfl_xor(c, 16);
            s += __shfl_xor(s, 32); c += __shfl_xor(c, 32);
            float n = (s - 1.0f) / c;
            bool done = (n <= tau);
            tau = fmaxf(tau, n);
            if (__all(done)) break;
        }

        float* ob = out + (size_t)myrow * D;
#pragma unroll
        for (int ct = 0; ct < 16; ++ct) {
            int cc = ct * 16 + q * 4;
            f32x4 x = acc[ct];
            f32x4 r;
#pragma unroll
            for (int k = 0; k < 4; ++k) r[k] = fmaxf(x[k] - tau, 0.f);
            *reinterpret_cast<f32x4*>(&ob[cc]) = r;
        }
    }
}

extern "C" void kernel_launch(void* const* d_in, const int* in_sizes, int n_in,
                              void* d_out, int out_size, void* d_ws, size_t ws_size,
                              hipStream_t stream) {
    const float* a      = (const float*)d_in[0];
    const float* priors = (const float*)d_in[1];
    const float* W      = (const float*)d_in[2];
    // d_in[3] = b : unused — ghost-BN mean subtraction cancels any per-column bias.
    const float* gamma  = (const float*)d_in[4];
    const float* beta   = (const float*)d_in[5];
    float* out = (float*)d_out;
    _Float16* wp = (_Float16*)d_ws;   // 256*256 f16 = 128 KB packed W

    const int B = in_sizes[0] / D;        // 262144
    const int nchunks = B / VBS;          // 2048
    const int pairs   = nchunks / 2;      // 1024 (B is a multiple of 256 here)

    hipLaunchKernelGGL(pack_w_kernel, dim3(32), dim3(256), 0, stream, W, wp);

    int grid = 256, iters = pairs / 256;
    if (pairs % 256 != 0) { grid = pairs; iters = 1; }   // robustness fallback
    hipLaunchKernelGGL(fused_kernel, dim3(grid), dim3(1024), 0, stream,
                       a, priors, wp, gamma, beta, out, iters);
}

// Round 17
// 275.312 us; speedup vs baseline: 1.9959x; 1.9959x over previous
//
#include <hip/hip_runtime.h>

typedef __attribute__((ext_vector_type(4))) float f32x4;
typedef __attribute__((ext_vector_type(8))) _Float16 f16x8;

#define D 256          // D_in == D_out == 256
#define VBS 128        // ghost batch rows per chunk
#define BN_EPS 1e-5f

// ---------------------------------------------------------------- pack W
// Pack W[k][n] (f32, row-major 256x256) into f16 MFMA fragment order.
// frag value = W[kb*32+(l>>4)*8+j][ct*16+(l&15)], frag (kb,ct,lane) at
// wp + ((kb*16+ct)*64+lane)*8.
__global__ void pack_w_kernel(const float* __restrict__ W, _Float16* __restrict__ wp) {
    int idx = blockIdx.x * blockDim.x + threadIdx.x;   // [0, 8192)
    int kb  = idx >> 10;
    int rem = idx & 1023;
    int ct  = rem >> 6;
    int l   = rem & 63;
    int col = ct * 16 + (l & 15);
    int k0  = kb * 32 + ((l >> 4) << 3);
    f16x8 v;
#pragma unroll
    for (int j = 0; j < 8; ++j) v[j] = (_Float16)W[(k0 + j) * D + col];
    *reinterpret_cast<f16x8*>(wp + (size_t)idx * 8) = v;
}

// 16-lane (DPP row) all-lanes sum: VALU pipe only.
template <int CTRL>
__device__ __forceinline__ float row_ror_add(float x) {
    int v = __builtin_amdgcn_update_dpp(0, __builtin_bit_cast(int, x),
                                        CTRL, 0xF, 0xF, true);
    return x + __builtin_bit_cast(float, v);
}
__device__ __forceinline__ float rsum16(float x) {
    x = row_ror_add<0x128>(x);
    x = row_ror_add<0x124>(x);
    x = row_ror_add<0x122>(x);
    x = row_ror_add<0x121>(x);
    return x;
}

#define GLL16(g, l)                                                     \
    __builtin_amdgcn_global_load_lds(                                   \
        (const __attribute__((address_space(1))) unsigned*)(g),         \
        (__attribute__((address_space(3))) unsigned*)(l), 16, 0, 0)

// LDS map (bytes):
//   [0,131072)        full packed W, resident for the whole kernel
//   [131072,139264)   sSum[8][256]     [139264,147456) sSq[8][256]
//   [147456,148480)   sA               [148480,149504) sB
//
// PERSISTENT blocks (grid=256), 512 thr (8 waves, 2/SIMD — occupancy is a
// closed axis: acc=64 AGPR/thread spills at any higher wave count, proven
// R7/R13/R16). The lever here is QUEUE DEPTH (Little's law: ~9 KB/CU
// outstanding needed for peak HBM; R15 averaged ~4):
//   - 4-deep rotating a-window (32 regs): refill->consume distance
//     ~800 cy ≈ HBM latency, issued before the dependent cvt
//   - priors[16] prefetched ONE PHASE EARLY (issued right after the
//     previous apply where p dies) -> 16 KB/wave in flight across
//     tau/stores AND the next K-loop
//   - next chunk's a-slots issued before the stats barriers
// K-loop is fully unrolled and barrier-free (W read-only in LDS).
// TRANSPOSED mfma: acc[ct] = mfma(W-frag, a-frag); lane = row
// (chunk*128 + wid*16 + (lane&15)), cols ct*16 + (lane>>4)*4 + {0..3}.
__global__ __launch_bounds__(512)
void fused_kernel(const float* __restrict__ A, const float* __restrict__ priors,
                  const _Float16* __restrict__ Wp, const float* __restrict__ gamma,
                  const float* __restrict__ beta, float* __restrict__ out, int iters) {
    const int tid  = threadIdx.x;
    const int wid  = tid >> 6;    // 0..7
    const int lane = tid & 63;
    const int lrow = lane & 15;
    const int q    = lane >> 4;

    __shared__ char smem[149504];

    // ---- prologue: stage the full 128 KB W into LDS once ----
    {
        const char* ws = (const char*)Wp + (size_t)tid * 16;
        char* wd = smem + (size_t)tid * 16;
#pragma unroll
        for (int j = 0; j < 16; ++j) GLL16(ws + j * 8192, wd + j * 8192);
    }
    __syncthreads();   // one-time drain; W is read-only from here on

    float* sSum = (float*)(smem + 131072);
    float* sSq  = (float*)(smem + 139264);
    float* sA   = (float*)(smem + 147456);
    float* sB   = (float*)(smem + 148480);

    const int c0 = blockIdx.x;
    const int GRID = gridDim.x;
    // a-frag for this thread: row = chunk*128 + wid*16 + lrow, k = kb*32+q*8+{0..7}
    const float* abase = A + (size_t)(c0 * VBS + wid * 16 + lrow) * D + q * 8;
    const size_t CSTR = (size_t)GRID * VBS * D;   // floats per chunk stride

    // 4-deep rotating a window (named slots -> static indexing, no scratch)
    f32x4 aL0, aH0, aL1, aH1, aL2, aH2, aL3, aH3;
#define LOADSLOT(s, ptr) do { aL##s = *reinterpret_cast<const f32x4*>(ptr); \
                              aH##s = *reinterpret_cast<const f32x4*>((ptr) + 4); } while (0)
    LOADSLOT(0, abase);
    LOADSLOT(1, abase + 32);
    LOADSLOT(2, abase + 64);
    LOADSLOT(3, abase + 96);

    // first chunk's priors: issued in the prologue so they fly under the K-loop
    const int row0 = c0 * VBS + wid * 16 + lrow;
    f32x4 p[16];
    {
        const float* pr = priors + (size_t)row0 * D;
#pragma unroll
        for (int ct = 0; ct < 16; ++ct)
            p[ct] = *reinterpret_cast<const f32x4*>(pr + ct * 16 + q * 4);
    }

#pragma unroll 1
    for (int it = 0; it < iters; ++it) {
        const int myrow = row0 + it * GRID * VBS;
        const float* ac = abase + (size_t)it * CSTR;

        f32x4 acc[16];
#pragma unroll
        for (int ct = 0; ct < 16; ++ct) { f32x4 z = {0.f, 0.f, 0.f, 0.f}; acc[ct] = z; }

        // ---- K-loop: barrier-free; 4-deep window, refill issued pre-cvt ----
#pragma unroll
        for (int kb = 0; kb < 8; ++kb) {
            if (kb < 4) {   // refill the slot consumed at kb with step kb+4
                const float* an = ac + (kb + 4) * 32;
                // consume current slot FIRST into locals, then overwrite
                f32x4 al = (kb == 0) ? aL0 : (kb == 1) ? aL1 : (kb == 2) ? aL2 : aL3;
                f32x4 ah = (kb == 0) ? aH0 : (kb == 1) ? aH1 : (kb == 2) ? aH2 : aH3;
                if (kb == 0) LOADSLOT(0, an);
                else if (kb == 1) LOADSLOT(1, an);
                else if (kb == 2) LOADSLOT(2, an);
                else LOADSLOT(3, an);
                f16x8 t;
#pragma unroll
                for (int j = 0; j < 4; ++j) { t[j] = (_Float16)al[j]; t[j + 4] = (_Float16)ah[j]; }
                const char* wb = smem + kb * 16384 + lane * 16;
#pragma unroll
                for (int ct = 0; ct < 16; ++ct) {
                    f16x8 w = *reinterpret_cast<const f16x8*>(wb + ct * 1024);
                    acc[ct] = __builtin_amdgcn_mfma_f32_16x16x32_f16(w, t, acc[ct], 0, 0, 0);
                }
            } else {
                f32x4 al = (kb == 4) ? aL0 : (kb == 5) ? aL1 : (kb == 6) ? aL2 : aL3;
                f32x4 ah = (kb == 4) ? aH0 : (kb == 5) ? aH1 : (kb == 6) ? aH2 : aH3;
                f16x8 t;
#pragma unroll
                for (int j = 0; j < 4; ++j) { t[j] = (_Float16)al[j]; t[j + 4] = (_Float16)ah[j]; }
                const char* wb = smem + kb * 16384 + lane * 16;
#pragma unroll
                for (int ct = 0; ct < 16; ++ct) {
                    f16x8 w = *reinterpret_cast<const f16x8*>(wb + ct * 1024);
                    acc[ct] = __builtin_amdgcn_mfma_f32_16x16x32_f16(w, t, acc[ct], 0, 0, 0);
                }
            }
        }

        // ---- next chunk's a window (4-deep): flies through the barriers ----
        if (it + 1 < iters) {
            const float* an = ac + CSTR;
            LOADSLOT(0, an);
            LOADSLOT(1, an + 32);
            LOADSLOT(2, an + 64);
            LOADSLOT(3, an + 96);
        }

        // ---- Ghost BN stats (DPP rsum16 per 16-row strip; LDS combine) ----
#pragma unroll
        for (int ct = 0; ct < 16; ++ct) {
            f32x4 s = acc[ct];
            f32x4 qv = s * s;
#pragma unroll
            for (int c = 0; c < 4; ++c) { s[c] = rsum16(s[c]); qv[c] = rsum16(qv[c]); }
            if (lrow == 0) {
                *reinterpret_cast<f32x4*>(&sSum[wid * D + ct * 16 + q * 4]) = s;
                *reinterpret_cast<f32x4*>(&sSq [wid * D + ct * 16 + q * 4]) = qv;
            }
        }
        // raw barrier: protect LDS stats only; vmem (p, a) stays in flight
        asm volatile("s_waitcnt lgkmcnt(0)" ::: "memory");
        __builtin_amdgcn_s_barrier();
        asm volatile("" ::: "memory");
        if (tid < D) {
            float s = 0.f, qq = 0.f;
#pragma unroll
            for (int w = 0; w < 8; ++w) { s += sSum[w * D + tid]; qq += sSq[w * D + tid]; }
            float mean = s * (1.0f / 128.0f);
            float var  = qq * (1.0f / 128.0f) - mean * mean;
            float g    = gamma[tid] * rsqrtf(var + BN_EPS);
            sA[tid] = g;
            sB[tid] = beta[tid] - mean * g;
        }
        asm volatile("s_waitcnt lgkmcnt(0)" ::: "memory");
        __builtin_amdgcn_s_barrier();
        asm volatile("" ::: "memory");

        // ---- apply BN * priors; track row max AND row sum ----
        float m = -1e30f, ssum = 0.f;
#pragma unroll
        for (int ct = 0; ct < 16; ++ct) {
            int cc = ct * 16 + q * 4;
            f32x4 ga = *reinterpret_cast<const f32x4*>(&sA[cc]);
            f32x4 bb = *reinterpret_cast<const f32x4*>(&sB[cc]);
            f32x4 x  = (acc[ct] * ga + bb) * p[ct];
            acc[ct] = x;
            m = fmaxf(m, fmaxf(fmaxf(x[0], x[1]), fmaxf(x[2], x[3])));
            ssum += (x[0] + x[1]) + (x[2] + x[3]);
        }
        m = fmaxf(m, __shfl_xor(m, 16));
        m = fmaxf(m, __shfl_xor(m, 32));
        ssum += __shfl_xor(ssum, 16);
        ssum += __shfl_xor(ssum, 32);

        // ---- p is dead now: prefetch NEXT chunk's priors immediately ----
        // (16 KB/wave in flight across tau + stores + next K-loop)
        if (it + 1 < iters) {
            const float* prn = priors + (size_t)(myrow + GRID * VBS) * D;
#pragma unroll
            for (int ct = 0; ct < 16; ++ct)
                p[ct] = *reinterpret_cast<const f32x4*>(prn + ct * 16 + q * 4);
        }

        // Michelot fixed-point. Both seeds provably <= tau*:
        //   m-1 (max support) and (sum_all-1)/256 (full support step).
        float tau = fmaxf(m - 1.0f, (ssum - 1.0f) * (1.0f / 256.0f));
#pragma unroll 1
        for (int itr = 0; itr < 32; ++itr) {
            float s = 0.f, c = 0.f;
#pragma unroll
            for (int ct = 0; ct < 16; ++ct)
#pragma unroll
                for (int k = 0; k < 4; ++k) {
                    float zz = acc[ct][k];
                    if (zz > tau) { s += zz; c += 1.f; }
                }
            s += __shfl_xor(s, 16); c += __shfl_xor(c, 16);
            s += __shfl_xor(s, 32); c += __shfl_xor(c, 32);
            float n = (s - 1.0f) / c;
            bool done = (n <= tau);
            tau = fmaxf(tau, n);
            if (__all(done)) break;
        }

        float* ob = out + (size_t)myrow * D;
#pragma unroll
        for (int ct = 0; ct < 16; ++ct) {
            int cc = ct * 16 + q * 4;
            f32x4 x = acc[ct];
            f32x4 r;
#pragma unroll
            for (int k = 0; k < 4; ++k) r[k] = fmaxf(x[k] - tau, 0.f);
            *reinterpret_cast<f32x4*>(&ob[cc]) = r;
        }
    }
#undef LOADSLOT
}

extern "C" void kernel_launch(void* const* d_in, const int* in_sizes, int n_in,
                              void* d_out, int out_size, void* d_ws, size_t ws_size,
                              hipStream_t stream) {
    const float* a      = (const float*)d_in[0];
    const float* priors = (const float*)d_in[1];
    const float* W      = (const float*)d_in[2];
    // d_in[3] = b : unused — ghost-BN mean subtraction cancels any per-column bias.
    const float* gamma  = (const float*)d_in[4];
    const float* beta   = (const float*)d_in[5];
    float* out = (float*)d_out;
    _Float16* wp = (_Float16*)d_ws;   // 256*256 f16 = 128 KB packed W

    const int B = in_sizes[0] / D;        // 262144
    const int nchunks = B / VBS;          // 2048

    hipLaunchKernelGGL(pack_w_kernel, dim3(32), dim3(256), 0, stream, W, wp);

    int grid = 256, iters = nchunks / 256;
    if (nchunks % 256 != 0) { grid = nchunks; iters = 1; }   // robustness fallback
    hipLaunchKernelGGL(fused_kernel, dim3(grid), dim3(512), 0, stream,
                       a, priors, wp, gamma, beta, out, iters);
}

// Round 18
// 270.374 us; speedup vs baseline: 2.0324x; 1.0183x over previous
//
#include <hip/hip_runtime.h>

typedef __attribute__((ext_vector_type(4))) float f32x4;
typedef __attribute__((ext_vector_type(8))) _Float16 f16x8;
typedef __attribute__((ext_vector_type(4))) int i32x4;

#define D 256          // D_in == D_out == 256
#define VBS 128        // ghost batch rows per chunk
#define BN_EPS 1e-5f

// ---------------------------------------------------------------- pack W
// Pack W[k][n] (f32, row-major 256x256) into f16 MFMA fragment order.
// frag value = W[kb*32+(l>>4)*8+j][ct*16+(l&15)], frag (kb,ct,lane) at
// wp + ((kb*16+ct)*64+lane)*8.
__global__ void pack_w_kernel(const float* __restrict__ W, _Float16* __restrict__ wp) {
    int idx = blockIdx.x * blockDim.x + threadIdx.x;   // [0, 8192)
    int kb  = idx >> 10;
    int rem = idx & 1023;
    int ct  = rem >> 6;
    int l   = rem & 63;
    int col = ct * 16 + (l & 15);
    int k0  = kb * 32 + ((l >> 4) << 3);
    f16x8 v;
#pragma unroll
    for (int j = 0; j < 8; ++j) v[j] = (_Float16)W[(k0 + j) * D + col];
    *reinterpret_cast<f16x8*>(wp + (size_t)idx * 8) = v;
}

// 16-lane (DPP row) all-lanes sum: VALU pipe only.
template <int CTRL>
__device__ __forceinline__ float row_ror_add(float x) {
    int v = __builtin_amdgcn_update_dpp(0, __builtin_bit_cast(int, x),
                                        CTRL, 0xF, 0xF, true);
    return x + __builtin_bit_cast(float, v);
}
__device__ __forceinline__ float rsum16(float x) {
    x = row_ror_add<0x128>(x);
    x = row_ror_add<0x124>(x);
    x = row_ror_add<0x122>(x);
    x = row_ror_add<0x121>(x);
    return x;
}

#define GLL16(g, l)                                                     \
    __builtin_amdgcn_global_load_lds(                                   \
        (const __attribute__((address_space(1))) unsigned*)(g),         \
        (__attribute__((address_space(3))) unsigned*)(l), 16, 0, 0)

#define RAWBAR() do {                                          \
        asm volatile("s_waitcnt lgkmcnt(0)" ::: "memory");     \
        __builtin_amdgcn_s_barrier();                          \
        asm volatile("" ::: "memory");                         \
    } while (0)

// LDS map (bytes):
//   [0,131072)        full packed W, resident
//   [131072,139264)   sSum[8][256]   [139264,147456) sSq[8][256]
//   [147456,148480)   sA             [148480,149504) sB
//   [149504,149568)   doneA[16]
//   overlays on dead sSum/sSq after sA/sB are built:
//   mP [2][128] @131072 | sP [2][128] @132096 | tS [2][2][128] @133120
//   tC [2][2][128] @137216
//
// 1024 threads = 16 waves = 8 row-strips x 2 col-halves; 4 waves/SIMD.
// acc = 16 rows x 128 cols / 64 = 32 regs/thread -> fits the 128-reg
// budget (R16's acc=64 did not). Rows are split across wave pairs, so
// sparsemax reductions exchange 2 floats/row via LDS per tau iteration
// (1 raw barrier each) with a one-iteration-lagged block-uniform done
// flag. W resident in LDS; barrier-free K-loop; 2-deep a-window.
__global__ __launch_bounds__(1024)
void fused_kernel(const float* __restrict__ A, const float* __restrict__ priors,
                  const _Float16* __restrict__ Wp, const float* __restrict__ gamma,
                  const float* __restrict__ beta, float* __restrict__ out, int iters) {
    const int tid  = threadIdx.x;
    const int lane = tid & 63;
    const int wid  = tid >> 6;   // 0..15
    const int cg   = wid & 1;    // column half (128 cols)
    const int rs   = wid >> 1;   // row strip  (16 rows)
    const int lrow = lane & 15;
    const int q    = lane >> 4;

    __shared__ char smem[149568];

    // ---- prologue: stage the full 128 KB W into LDS once ----
    {
        const char* ws = (const char*)Wp + (size_t)tid * 16;
        char* wd = smem + (size_t)tid * 16;
#pragma unroll
        for (int j = 0; j < 8; ++j) GLL16(ws + j * 16384, wd + j * 16384);
    }
    __syncthreads();   // one-time drain; W read-only afterwards

    float* sSum  = (float*)(smem + 131072);
    float* sSq   = (float*)(smem + 139264);
    float* sA    = (float*)(smem + 147456);
    float* sB    = (float*)(smem + 148480);
    int*   doneA = (int*)  (smem + 149504);
    float* mP    = (float*)(smem + 131072);   // overlay
    float* sP    = (float*)(smem + 132096);   // overlay
    float* tS    = (float*)(smem + 133120);   // overlay [2][2][128]
    float* tC    = (float*)(smem + 137216);   // overlay [2][2][128]

    const int c0 = blockIdx.x;
    const int GRID = gridDim.x;
    // a-row for this thread: chunk*128 + rs*16 + lrow (both cg waves load the
    // same rows -> L1 dedup, no extra HBM). k = kb*32 + q*8 + {0..7}.
    const float* abase = A + (size_t)(c0 * VBS + rs * 16 + lrow) * D + q * 8;
    const size_t CSTR = (size_t)GRID * VBS * D;
    const int wofs = cg * 8192;   // byte offset of this half's frags in a kb slab
    const int row  = rs * 16 + lrow;   // row index within the chunk

    f32x4 aL0, aH0, aL1, aH1;
#define LOADSLOT(s, ptr) do { aL##s = *reinterpret_cast<const f32x4*>(ptr); \
                              aH##s = *reinterpret_cast<const f32x4*>((ptr) + 4); } while (0)
    LOADSLOT(0, abase);
    LOADSLOT(1, abase + 32);

#pragma unroll 1
    for (int it = 0; it < iters; ++it) {
        const int myrow = (c0 + it * GRID) * VBS + row;
        const float* ac = abase + (size_t)it * CSTR;

        f32x4 acc[8];
#pragma unroll
        for (int ct = 0; ct < 8; ++ct) { f32x4 z = {0.f, 0.f, 0.f, 0.f}; acc[ct] = z; }

        // ---- K-loop: barrier-free; 2-deep a window ----
#pragma unroll
        for (int kb = 0; kb < 8; ++kb) {
            f32x4 al = (kb & 1) ? aL1 : aL0;
            f32x4 ah = (kb & 1) ? aH1 : aH0;
            if (kb < 6) {
                const float* an = ac + (kb + 2) * 32;
                if (kb & 1) LOADSLOT(1, an); else LOADSLOT(0, an);
            }
            f16x8 t;
#pragma unroll
            for (int j = 0; j < 4; ++j) { t[j] = (_Float16)al[j]; t[j + 4] = (_Float16)ah[j]; }
            const char* wb = smem + kb * 16384 + wofs + lane * 16;
#pragma unroll
            for (int ct = 0; ct < 8; ++ct) {
                f16x8 w = *reinterpret_cast<const f16x8*>(wb + ct * 1024);
                acc[ct] = __builtin_amdgcn_mfma_f32_16x16x32_f16(w, t, acc[ct], 0, 0, 0);
            }
        }

        // ---- next chunk's a window: flies through the barriers ----
        if (it + 1 < iters) {
            const float* an = ac + CSTR;
            LOADSLOT(0, an);
            LOADSLOT(1, an + 32);
        }

        // ---- Ghost BN stats (DPP rsum16 over the strip's 16 rows) ----
#pragma unroll
        for (int ct = 0; ct < 8; ++ct) {
            f32x4 s = acc[ct];
            f32x4 qv = s * s;
#pragma unroll
            for (int c = 0; c < 4; ++c) { s[c] = rsum16(s[c]); qv[c] = rsum16(qv[c]); }
            if (lrow == 0) {
                const int cc = cg * 128 + ct * 16 + q * 4;
                *reinterpret_cast<f32x4*>(&sSum[rs * D + cc]) = s;
                *reinterpret_cast<f32x4*>(&sSq [rs * D + cc]) = qv;
            }
        }
        RAWBAR();
        if (tid < D) {
            float s = 0.f, qq = 0.f;
#pragma unroll
            for (int w = 0; w < 8; ++w) { s += sSum[w * D + tid]; qq += sSq[w * D + tid]; }
            float mean = s * (1.0f / 128.0f);
            float var  = qq * (1.0f / 128.0f) - mean * mean;
            float g    = gamma[tid] * rsqrtf(var + BN_EPS);
            sA[tid] = g;
            sB[tid] = beta[tid] - mean * g;
        }
        RAWBAR();

        // ---- apply BN * priors (JIT batches of 4); half-row max + sum ----
        const float* prb = priors + (size_t)myrow * D + cg * 128;
        float m = -1e30f, ss = 0.f;
#pragma unroll 1
        for (int g2 = 0; g2 < 2; ++g2) {
            f32x4 pv0 = *reinterpret_cast<const f32x4*>(prb + (g2 * 4 + 0) * 16 + q * 4);
            f32x4 pv1 = *reinterpret_cast<const f32x4*>(prb + (g2 * 4 + 1) * 16 + q * 4);
            f32x4 pv2 = *reinterpret_cast<const f32x4*>(prb + (g2 * 4 + 2) * 16 + q * 4);
            f32x4 pv3 = *reinterpret_cast<const f32x4*>(prb + (g2 * 4 + 3) * 16 + q * 4);
#pragma unroll
            for (int j = 0; j < 4; ++j) {
                const int ct = g2 * 4 + j;
                const int cc = cg * 128 + ct * 16 + q * 4;
                f32x4 ga = *reinterpret_cast<const f32x4*>(&sA[cc]);
                f32x4 bb = *reinterpret_cast<const f32x4*>(&sB[cc]);
                f32x4 pv = (j == 0) ? pv0 : (j == 1) ? pv1 : (j == 2) ? pv2 : pv3;
                f32x4 x  = (acc[ct] * ga + bb) * pv;
                acc[ct] = x;
                m = fmaxf(m, fmaxf(fmaxf(x[0], x[1]), fmaxf(x[2], x[3])));
                ss += (x[0] + x[1]) + (x[2] + x[3]);
            }
        }
        m  = fmaxf(m, __shfl_xor(m, 16)); m  = fmaxf(m, __shfl_xor(m, 32));
        ss += __shfl_xor(ss, 16);         ss += __shfl_xor(ss, 32);

        // ---- seed exchange: combine the two col-halves of each row ----
        if (lane < 16) { mP[cg * 128 + rs * 16 + lane] = m; sP[cg * 128 + rs * 16 + lane] = ss; }
        RAWBAR();
        float M  = fmaxf(mP[row], mP[128 + row]);
        float SS = sP[row] + sP[128 + row];
        // Michelot seeds, both provably <= tau*.
        float tau = fmaxf(M - 1.0f, (SS - 1.0f) * (1.0f / 256.0f));

        // ---- tau loop: cross-wave partials via LDS, lagged done flag ----
        int prev_done = 0;
        int buf = 0;
#pragma unroll 1
        for (int itr = 0; itr < 32; ++itr) {
            float s = 0.f, c = 0.f;
#pragma unroll
            for (int ct = 0; ct < 8; ++ct)
#pragma unroll
                for (int k = 0; k < 4; ++k) {
                    float zz = acc[ct][k];
                    if (zz > tau) { s += zz; c += 1.f; }
                }
            s += __shfl_xor(s, 16); c += __shfl_xor(c, 16);
            s += __shfl_xor(s, 32); c += __shfl_xor(c, 32);
            if (lane < 16) {
                tS[(buf * 2 + cg) * 128 + rs * 16 + lane] = s;
                tC[(buf * 2 + cg) * 128 + rs * 16 + lane] = c;
            }
            if (lane == 0) doneA[wid] = prev_done;
            RAWBAR();
            // block consensus of the PREVIOUS iteration (uniform across waves)
            i32x4 d0 = *reinterpret_cast<const i32x4*>(doneA);
            i32x4 d1 = *reinterpret_cast<const i32x4*>(doneA + 4);
            i32x4 d2 = *reinterpret_cast<const i32x4*>(doneA + 8);
            i32x4 d3 = *reinterpret_cast<const i32x4*>(doneA + 12);
            int alld = d0[0] & d0[1] & d0[2] & d0[3] & d1[0] & d1[1] & d1[2] & d1[3]
                     & d2[0] & d2[1] & d2[2] & d2[3] & d3[0] & d3[1] & d3[2] & d3[3];
            if (alld) break;
            float S = tS[(buf * 2 + 0) * 128 + row] + tS[(buf * 2 + 1) * 128 + row];
            float C = tC[(buf * 2 + 0) * 128 + row] + tC[(buf * 2 + 1) * 128 + row];
            float n = (S - 1.0f) / C;
            prev_done = __all(n <= tau) ? 1 : 0;
            tau = fmaxf(tau, n);
            buf ^= 1;
        }

        // ---- store ----
        float* ob = out + (size_t)myrow * D + cg * 128;
#pragma unroll
        for (int ct = 0; ct < 8; ++ct) {
            const int cc = ct * 16 + q * 4;
            f32x4 x = acc[ct];
            f32x4 r;
#pragma unroll
            for (int k = 0; k < 4; ++k) r[k] = fmaxf(x[k] - tau, 0.f);
            *reinterpret_cast<f32x4*>(&ob[cc]) = r;
        }
    }
#undef LOADSLOT
}

extern "C" void kernel_launch(void* const* d_in, const int* in_sizes, int n_in,
                              void* d_out, int out_size, void* d_ws, size_t ws_size,
                              hipStream_t stream) {
    const float* a      = (const float*)d_in[0];
    const float* priors = (const float*)d_in[1];
    const float* W      = (const float*)d_in[2];
    // d_in[3] = b : unused — ghost-BN mean subtraction cancels any per-column bias.
    const float* gamma  = (const float*)d_in[4];
    const float* beta   = (const float*)d_in[5];
    float* out = (float*)d_out;
    _Float16* wp = (_Float16*)d_ws;   // 256*256 f16 = 128 KB packed W

    const int B = in_sizes[0] / D;        // 262144
    const int nchunks = B / VBS;          // 2048

    hipLaunchKernelGGL(pack_w_kernel, dim3(32), dim3(256), 0, stream, W, wp);

    int grid = 256, iters = nchunks / 256;
    if (nchunks % 256 != 0) { grid = nchunks; iters = 1; }   // robustness fallback
    hipLaunchKernelGGL(fused_kernel, dim3(grid), dim3(1024), 0, stream,
                       a, priors, wp, gamma, beta, out, iters);
}

// Round 19
// 208.129 us; speedup vs baseline: 2.6402x; 1.2991x over previous
//
#include <hip/hip_runtime.h>

typedef __attribute__((ext_vector_type(4))) float f32x4;
typedef __attribute__((ext_vector_type(8))) _Float16 f16x8;

#define D 256          // D_in == D_out == 256
#define VBS 128        // ghost batch rows per chunk
#define BN_EPS 1e-5f

// ---------------------------------------------------------------- pack W
// Pack W[k][n] (f32, row-major 256x256) into f16 MFMA fragment order.
// frag value = W[kb*32+(l>>4)*8+j][ct*16+(l&15)], frag (kb,ct,lane) at
// wp + ((kb*16+ct)*64+lane)*8.
__global__ void pack_w_kernel(const float* __restrict__ W, _Float16* __restrict__ wp) {
    int idx = blockIdx.x * blockDim.x + threadIdx.x;   // [0, 8192)
    int kb  = idx >> 10;
    int rem = idx & 1023;
    int ct  = rem >> 6;
    int l   = rem & 63;
    int col = ct * 16 + (l & 15);
    int k0  = kb * 32 + ((l >> 4) << 3);
    f16x8 v;
#pragma unroll
    for (int j = 0; j < 8; ++j) v[j] = (_Float16)W[(k0 + j) * D + col];
    *reinterpret_cast<f16x8*>(wp + (size_t)idx * 8) = v;
}

// 16-lane (DPP row) all-lanes sum: VALU pipe only.
template <int CTRL>
__device__ __forceinline__ float row_ror_add(float x) {
    int v = __builtin_amdgcn_update_dpp(0, __builtin_bit_cast(int, x),
                                        CTRL, 0xF, 0xF, true);
    return x + __builtin_bit_cast(float, v);
}
__device__ __forceinline__ float rsum16(float x) {
    x = row_ror_add<0x128>(x);
    x = row_ror_add<0x124>(x);
    x = row_ror_add<0x122>(x);
    x = row_ror_add<0x121>(x);
    return x;
}

#define GLL16(g, l)                                                     \
    __builtin_amdgcn_global_load_lds(                                   \
        (const __attribute__((address_space(1))) unsigned*)(g),         \
        (__attribute__((address_space(3))) unsigned*)(l), 16, 0, 0)

// LDS map (bytes):
//   [0,131072)        full packed W, resident for the whole kernel
//   [131072,139264)   sSum[8][256]     [139264,147456) sSq[8][256]
//   [147456,148480)   sA               [148480,149504) sB
//
// PERSISTENT blocks (grid=256): W staged into LDS ONCE; per chunk:
//   - a loaded per-K-step into a 2-deep rotating 16-reg window
//   - K-loop: fully unrolled, BARRIER-FREE (W read-only, a in regs)
//   - 2 raw s_barriers/chunk (stats), lgkmcnt-only (no vmcnt drain:
//     priors prefetch and next-chunk a stay in flight across them)
// TRANSPOSED mfma: acc[ct] = mfma(W-frag, a-frag); lane holds row
// (chunk*128 + wid*16 + (lane&15)), cols ct*16 + (lane>>4)*4 + {0..3}.
// Session optimum: 209.7 us, FETCH 265 MB / WRITE 263 MB, 0 conflicts.
// Escapes tested and refuted: 4 waves/SIMD (R16 spill, R18 barrier tax),
// deeper reg queues (R17 spill), LDS pipelines (R11/12 neutral).
__global__ __launch_bounds__(512)
void fused_kernel(const float* __restrict__ A, const float* __restrict__ priors,
                  const _Float16* __restrict__ Wp, const float* __restrict__ gamma,
                  const float* __restrict__ beta, float* __restrict__ out, int iters) {
    const int tid  = threadIdx.x;
    const int wid  = tid >> 6;    // 0..7
    const int lane = tid & 63;
    const int lrow = lane & 15;
    const int q    = lane >> 4;

    __shared__ char smem[149504];

    // ---- prologue: stage the full 128 KB W into LDS once ----
    {
        const char* ws = (const char*)Wp + (size_t)tid * 16;
        char* wd = smem + (size_t)tid * 16;
#pragma unroll
        for (int j = 0; j < 16; ++j) GLL16(ws + j * 8192, wd + j * 8192);
    }
    __syncthreads();   // one-time drain; W is read-only from here on

    float* sSum = (float*)(smem + 131072);
    float* sSq  = (float*)(smem + 139264);
    float* sA   = (float*)(smem + 147456);
    float* sB   = (float*)(smem + 148480);

    const int c0 = blockIdx.x;
    const int GRID = gridDim.x;
    // a-frag for this thread: row = chunk*128 + wid*16 + lrow, k = kb*32+q*8+{0..7}
    const float* abase = A + (size_t)(c0 * VBS + wid * 16 + lrow) * D + q * 8;
    const size_t CSTR = (size_t)GRID * VBS * D;   // floats per chunk stride

    // 2-deep rotating a window (named slots -> static indexing, no scratch)
    f32x4 aL0, aH0, aL1, aH1;
    aL0 = *reinterpret_cast<const f32x4*>(abase);
    aH0 = *reinterpret_cast<const f32x4*>(abase + 4);
    aL1 = *reinterpret_cast<const f32x4*>(abase + 32);
    aH1 = *reinterpret_cast<const f32x4*>(abase + 36);

#pragma unroll 1
    for (int it = 0; it < iters; ++it) {
        const int myrow = (c0 + it * GRID) * VBS + wid * 16 + lrow;
        const float* ac = abase + (size_t)it * CSTR;

        f32x4 acc[16];
#pragma unroll
        for (int ct = 0; ct < 16; ++ct) { f32x4 z = {0.f, 0.f, 0.f, 0.f}; acc[ct] = z; }

        // ---- K-loop: barrier-free; a window rotates 2 steps ahead ----
#pragma unroll
        for (int kb = 0; kb < 8; ++kb) {
            f32x4 al = (kb & 1) ? aL1 : aL0;
            f32x4 ah = (kb & 1) ? aH1 : aH0;
            f16x8 t;
#pragma unroll
            for (int j = 0; j < 4; ++j) { t[j] = (_Float16)al[j]; t[j + 4] = (_Float16)ah[j]; }
            if (kb < 6) {   // refill the slot just consumed with step kb+2
                const float* an = ac + (kb + 2) * 32;
                if (kb & 1) { aL1 = *reinterpret_cast<const f32x4*>(an);
                              aH1 = *reinterpret_cast<const f32x4*>(an + 4); }
                else        { aL0 = *reinterpret_cast<const f32x4*>(an);
                              aH0 = *reinterpret_cast<const f32x4*>(an + 4); }
            }
            const char* wb = smem + kb * 16384 + lane * 16;
#pragma unroll
            for (int ct = 0; ct < 16; ++ct) {
                f16x8 w = *reinterpret_cast<const f16x8*>(wb + ct * 1024);
                acc[ct] = __builtin_amdgcn_mfma_f32_16x16x32_f16(w, t, acc[ct], 0, 0, 0);
            }
        }

        // ---- priors prefetch: flies through the stats barriers ----
        const float* pr = priors + (size_t)myrow * D;
        f32x4 p[16];
#pragma unroll
        for (int ct = 0; ct < 16; ++ct)
            p[ct] = *reinterpret_cast<const f32x4*>(pr + ct * 16 + q * 4);

        // ---- next chunk's first a window: also issued before the barriers ----
        if (it + 1 < iters) {
            const float* an = ac + CSTR;
            aL0 = *reinterpret_cast<const f32x4*>(an);
            aH0 = *reinterpret_cast<const f32x4*>(an + 4);
            aL1 = *reinterpret_cast<const f32x4*>(an + 32);
            aH1 = *reinterpret_cast<const f32x4*>(an + 36);
        }

        // ---- Ghost BN stats (DPP rsum16 per 16-row strip; LDS combine) ----
#pragma unroll
        for (int ct = 0; ct < 16; ++ct) {
            f32x4 s = acc[ct];
            f32x4 qv = s * s;
#pragma unroll
            for (int c = 0; c < 4; ++c) { s[c] = rsum16(s[c]); qv[c] = rsum16(qv[c]); }
            if (lrow == 0) {
                *reinterpret_cast<f32x4*>(&sSum[wid * D + ct * 16 + q * 4]) = s;
                *reinterpret_cast<f32x4*>(&sSq [wid * D + ct * 16 + q * 4]) = qv;
            }
        }
        // raw barrier: protect LDS stats only; vmem (p, a) stays in flight
        asm volatile("s_waitcnt lgkmcnt(0)" ::: "memory");
        __builtin_amdgcn_s_barrier();
        asm volatile("" ::: "memory");
        if (tid < D) {
            float s = 0.f, qq = 0.f;
#pragma unroll
            for (int w = 0; w < 8; ++w) { s += sSum[w * D + tid]; qq += sSq[w * D + tid]; }
            float mean = s * (1.0f / 128.0f);
            float var  = qq * (1.0f / 128.0f) - mean * mean;
            float g    = gamma[tid] * rsqrtf(var + BN_EPS);
            sA[tid] = g;
            sB[tid] = beta[tid] - mean * g;
        }
        asm volatile("s_waitcnt lgkmcnt(0)" ::: "memory");
        __builtin_amdgcn_s_barrier();
        asm volatile("" ::: "memory");

        // ---- apply BN * priors; track row max AND row sum ----
        float m = -1e30f, ssum = 0.f;
#pragma unroll
        for (int ct = 0; ct < 16; ++ct) {
            int cc = ct * 16 + q * 4;
            f32x4 ga = *reinterpret_cast<const f32x4*>(&sA[cc]);
            f32x4 bb = *reinterpret_cast<const f32x4*>(&sB[cc]);
            f32x4 x  = (acc[ct] * ga + bb) * p[ct];
            acc[ct] = x;
            m = fmaxf(m, fmaxf(fmaxf(x[0], x[1]), fmaxf(x[2], x[3])));
            ssum += (x[0] + x[1]) + (x[2] + x[3]);
        }
        m = fmaxf(m, __shfl_xor(m, 16));
        m = fmaxf(m, __shfl_xor(m, 32));
        ssum += __shfl_xor(ssum, 16);
        ssum += __shfl_xor(ssum, 32);

        // Michelot fixed-point. Both seeds provably <= tau*:
        //   m-1 (max support) and (sum_all-1)/256 (full support step).
        float tau = fmaxf(m - 1.0f, (ssum - 1.0f) * (1.0f / 256.0f));
#pragma unroll 1
        for (int itr = 0; itr < 32; ++itr) {
            float s = 0.f, c = 0.f;
#pragma unroll
            for (int ct = 0; ct < 16; ++ct)
#pragma unroll
                for (int k = 0; k < 4; ++k) {
                    float zz = acc[ct][k];
                    if (zz > tau) { s += zz; c += 1.f; }
                }
            s += __shfl_xor(s, 16); c += __shfl_xor(c, 16);
            s += __shfl_xor(s, 32); c += __shfl_xor(c, 32);
            float n = (s - 1.0f) / c;
            bool done = (n <= tau);
            tau = fmaxf(tau, n);
            if (__all(done)) break;
        }

        float* ob = out + (size_t)myrow * D;
#pragma unroll
        for (int ct = 0; ct < 16; ++ct) {
            int cc = ct * 16 + q * 4;
            f32x4 x = acc[ct];
            f32x4 r;
#pragma unroll
            for (int k = 0; k < 4; ++k) r[k] = fmaxf(x[k] - tau, 0.f);
            *reinterpret_cast<f32x4*>(&ob[cc]) = r;
        }
    }
}

extern "C" void kernel_launch(void* const* d_in, const int* in_sizes, int n_in,
                              void* d_out, int out_size, void* d_ws, size_t ws_size,
                              hipStream_t stream) {
    const float* a      = (const float*)d_in[0];
    const float* priors = (const float*)d_in[1];
    const float* W      = (const float*)d_in[2];
    // d_in[3] = b : unused — ghost-BN mean subtraction cancels any per-column bias.
    const float* gamma  = (const float*)d_in[4];
    const float* beta   = (const float*)d_in[5];
    float* out = (float*)d_out;
    _Float16* wp = (_Float16*)d_ws;   // 256*256 f16 = 128 KB packed W

    const int B = in_sizes[0] / D;        // 262144
    const int nchunks = B / VBS;          // 2048

    hipLaunchKernelGGL(pack_w_kernel, dim3(32), dim3(256), 0, stream, W, wp);

    int grid = 256, iters = nchunks / 256;
    if (nchunks % 256 != 0) { grid = nchunks; iters = 1; }   // robustness fallback
    hipLaunchKernelGGL(fused_kernel, dim3(grid), dim3(512), 0, stream,
                       a, priors, wp, gamma, beta, out, iters);
}